// Round 10
// baseline (211.653 us; speedup 1.0000x reference)
//
#include <hip/hip_runtime.h>
#include <hip/hip_bf16.h>
#include <math.h>

typedef unsigned long long u64;
typedef unsigned int u32;

#define A_TOTAL 24564
#define NCLS 80
#define NIMG 4
#define NPRE 2000
#define NLV 7
#define HBUCKETS 1024
#define BEXP_BASE 0x3CA3
#define TOTAL_G (NIMG * A_TOTAL)   // 98256
#define FA 64                      // anchors per block (fused/filter)
#define FT 256                     // threads per block (4 per anchor)
#define NBLK_F ((TOTAL_G + FA - 1) / FA)  // 1536
#define POOL_CAP_MAX 4096
#define CAPSEL 4608
#define NMST 1024                  // k_nms threads (16 waves)

__device__ __constant__ int c_klv[NLV] = {1000,1000,1000,1000,1000,1000,320};

// ---- workspace layout (bytes) ----
#define WS_HIST      0          // 28*1024*4 = 114688
#define WS_MCOUNT    114688     // 28*4
#define WS_BCOUNT    114800     // 28*4
#define WS_ZERO_END  114912     // hist+mcount+bcount only (pcount overwritten)
#define WS_PCOUNT    114912     // 1536*4 = 6144
#define WS_MAIN      121280     // 28*1024*8
#define WS_BND       350656     // 28*4096*8
#define WS_BOXES     1268160    // 4*2000*16
#define WS_CLS       1396160    // 4*2000*4
#define WS_SCORE     1428160    // 4*2000*4
#define WS_POOL      3508160    // NBLK_F * cap * 8, cap adaptive to ws_size

#define NZERO_W (WS_ZERO_END / 4)   // 28728 u32 words

__device__ inline u64 shfl_u64(u64 v, int src) {
  int lo = __shfl((int)(u32)(v & 0xFFFFFFFFULL), src);
  int hi = __shfl((int)(u32)(v >> 32), src);
  return ((u64)(u32)hi << 32) | (u32)lo;
}

__device__ inline int score_bucket(u32 bits) {
  int b = (int)(bits >> 16) - BEXP_BASE;
  return b < 0 ? 0 : (b > HBUCKETS - 1 ? HBUCKETS - 1 : b);
}

__device__ inline int level_of(int a) {
  return (a < 16384) ? 0 : (a < 22528) ? 1 : (a < 24064) ? 2 :
         (a < 24448) ? 3 : (a < 24544) ? 4 : (a < 24560) ? 5 : 6;
}

// replaces rocclr fillBufferAligned for our small zero region
__global__ __launch_bounds__(256) void k_zero(u32* __restrict__ p) {
  int i = blockIdx.x * 256 + threadIdx.x;
  if (i < NZERO_W) p[i] = 0;
}

// Registers-only softmax for one anchor, 4 threads/anchor (quad q=0..3 owns
// classes [20q,20q+20); q==3 also folds class 80 into max/sum). SINGLE
// source of truth so k_filter's fallback reproduces identical bits.
__device__ inline void score20(const float* __restrict__ logits, int g, int q,
                               float (&e)[20], float& rt) {
  const float* row = logits + (size_t)g * 81;
  float x[20];
#pragma unroll
  for (int i = 0; i < 20; ++i) x[i] = row[q * 20 + i];
  float x80 = (q == 3) ? row[80] : 0.f;
  float mloc = x[0];
#pragma unroll
  for (int i = 1; i < 20; ++i) mloc = fmaxf(mloc, x[i]);
  if (q == 3) mloc = fmaxf(mloc, x80);
  float m = fmaxf(mloc, __shfl_xor(mloc, 1));
  m = fmaxf(m, __shfl_xor(m, 2));
  float tq = 0.f;
#pragma unroll
  for (int i = 0; i < 20; ++i) { e[i] = expf(x[i] - m); tq += e[i]; }
  if (q == 3) tq += expf(x80 - m);
  float t = tq + __shfl_xor(tq, 1);
  t = t + __shfl_xor(t, 2);
  rt = 1.0f / t;
}

// One full wave finds (cut bucket, count-in-bucket) for top-k over a 1024-bin
// histogram h. Deterministic: same h,k -> same result.
__device__ inline void wave_find_cut(const u32* __restrict__ h, int k, int lane,
                                     int& cx, int& cy) {
  u32 s = 0;
#pragma unroll
  for (int i = 0; i < 16; ++i) s += h[lane * 16 + i];
  u32 S = s;  // inclusive suffix-sum across lanes
#pragma unroll
  for (int o = 1; o < 64; o <<= 1) {
    u32 t = (u32)__shfl_down((int)S, o);
    if (lane + o < 64) S += t;
  }
  u32 total = (u32)__shfl((int)S, 0);
  if (total <= (u32)k) { cx = -1; cy = 0; return; }
  u64 bm = __ballot(S >= (u32)k);
  int L0 = 63 - (int)__clzll((long long)bm);
  u32 Sup = (u32)__shfl_down((int)S, 1);
  if (lane == 63) Sup = 0;
  int rcx = 0, rcy = 0;
  if (lane == L0) {
    u32 cum = Sup;
    for (int i = 15; i >= 0; --i) {
      u32 c = h[lane * 16 + i];
      if (cum + c >= (u32)k) { rcx = lane * 16 + i; rcy = k - (int)cum; break; }
      cum += c;
    }
  }
  cx = __shfl(rcx, L0);
  cy = __shfl(rcy, L0);
}

// Single scoring pass: registers-only softmax, per-seg score histogram,
// emission of ALL above-threshold keys into this block's pool slice.
__global__ __launch_bounds__(FT) void k_fused(const float* __restrict__ logits,
                                              u32* __restrict__ histG,
                                              u64* __restrict__ pool,
                                              u32* __restrict__ pcount, int cap) {
  __shared__ u32 sh[HBUCKETS];    // 4096 B
  __shared__ int nm;
  int tid = threadIdx.x, bx = blockIdx.x;
  for (int b = tid; b < HBUCKETS; b += FT) sh[b] = 0;
  if (tid == 0) nm = 0;
  int la = tid >> 2, q = tid & 3;
  int g = bx * FA + la;
  bool valid = g < TOTAL_G;
  int g0 = bx * FA;
  int seg0 = (g0 / A_TOTAL) * NLV + level_of(g0 % A_TOTAL);
  int seg = seg0, a = 0;
  float e[20];
  float rt = 0.f;
  if (valid) {
    int img = g / A_TOTAL;
    a = g - img * A_TOTAL;
    seg = img * NLV + level_of(a);
    score20(logits, g, q, e, rt);
  }
  int uniform = __syncthreads_and((int)(!valid || seg == seg0));
  if (valid) {
    u32* hdst = uniform ? sh : (histG + (size_t)seg * HBUCKETS);
    int c0 = q * 20;
    u32 wmask = 0;
#pragma unroll
    for (int i = 0; i < 20; ++i) {
      float s = e[i] * rt;
      if (s > 0.02f) wmask |= (1u << i);
    }
    int cnt = __popc(wmask);
    int basep = 0;
    if (cnt) basep = atomicAdd(&nm, cnt);
    while (wmask) {
      int i = __ffs(wmask) - 1;
      wmask &= wmask - 1;
      float s = e[i] * rt;
      u32 bits = __float_as_uint(s);
      atomicAdd(&hdst[score_bucket(bits)], 1u);
      if (basep < cap)
        pool[(size_t)bx * cap + basep] =
            ((u64)bits << 32) | (u64)(0xFFFFFFFFu - (u32)(a * NCLS + c0 + i));
      ++basep;
    }
  }
  __syncthreads();
  if (uniform) {
    u32* hseg = histG + (size_t)seg0 * HBUCKETS;
    for (int b = tid; b < HBUCKETS; b += FT) {
      u32 v = sh[b];
      if (v) atomicAdd(&hseg[b], v);
    }
  }
  if (tid == 0) pcount[bx] = (u32)nm;
}

// Stream this block's pool slice; per-block cut re-derivation (<=4 segs,
// deterministic from histG). Fallback (pool overflow, statistically never):
// registers-only recompute via score20 -> identical bits.
__global__ __launch_bounds__(FT) void k_filter(const float* __restrict__ logits,
                                               const u64* __restrict__ pool,
                                               const u32* __restrict__ pcount,
                                               const u32* __restrict__ histG, int cap,
                                               u64* __restrict__ mainG, u32* __restrict__ mcount,
                                               u64* __restrict__ bndG, u32* __restrict__ bcount) {
  __shared__ int lcx4[4];
  __shared__ u64 mk[1024]; __shared__ unsigned char msg_[1024];
  __shared__ u64 bkl[256]; __shared__ unsigned char bsg[256];
  __shared__ int nm, nb, cm[4], cb[4], basem[4], baseb[4], wm[4], wb[4];
  int tid = threadIdx.x, bx = blockIdx.x;
  if (tid < 4) { cm[tid] = 0; cb[tid] = 0; wm[tid] = 0; wb[tid] = 0; }
  if (tid == 0) { nm = 0; nb = 0; }
  int g0 = bx * FA;
  int img0 = g0 / A_TOTAL;
  int alo = g0 - img0 * A_TOTAL;
  int gN = g0 + FA - 1; if (gN > TOTAL_G - 1) gN = TOTAL_G - 1;
  int seg_lo = img0 * NLV + level_of(alo);
  int seg_hi = (gN / A_TOTAL) * NLV + level_of(gN % A_TOTAL);
  int nseg = seg_hi - seg_lo + 1;   // <= 4 by construction
  int wid = tid >> 6, lane = tid & 63;
  if (wid < nseg) {
    int cx, cy;
    wave_find_cut(histG + (size_t)(seg_lo + wid) * HBUCKETS,
                  c_klv[(seg_lo + wid) % NLV], lane, cx, cy);
    if (lane == 0) lcx4[wid] = cx;
  }
  __syncthreads();
  int n = (int)pcount[bx];
  if (n <= cap) {
    for (int t = tid; t < n; t += FT) {
      u64 key = pool[(size_t)bx * cap + t];
      u32 bits = (u32)(key >> 32);
      u32 flat = 0xFFFFFFFFu - (u32)(key & 0xFFFFFFFFULL);
      int a = (int)(flat / NCLS);
      int img = (a >= alo) ? img0 : img0 + 1;
      int seg = img * NLV + level_of(a);
      int si = seg - seg_lo;
      int ctx = lcx4[si];
      int bk = score_bucket(bits);
      if (ctx < 0 || bk > ctx) {
        int p = atomicAdd(&nm, 1);
        if (p < 1024) { mk[p] = key; msg_[p] = (unsigned char)si; atomicAdd(&cm[si], 1); }
        else { u32 pg = atomicAdd(&mcount[seg], 1u); if (pg < 1024) mainG[(size_t)seg * 1024 + pg] = key; }
      } else if (bk == ctx) {
        int p = atomicAdd(&nb, 1);
        if (p < 256) { bkl[p] = key; bsg[p] = (unsigned char)si; atomicAdd(&cb[si], 1); }
        else { u32 pg = atomicAdd(&bcount[seg], 1u); if (pg < 4096) bndG[(size_t)seg * 4096 + pg] = key; }
      }
    }
  } else {
    int la = tid >> 2, q = tid & 3;
    int g = g0 + la;
    if (g < TOTAL_G) {
      int img = g / A_TOTAL;
      int a = g - img * A_TOTAL;
      int seg = img * NLV + level_of(a);
      int si = seg - seg_lo;
      int ctx = lcx4[si];
      float e[20];
      float rt;
      score20(logits, g, q, e, rt);
      int c0 = q * 20;
      for (int i = 0; i < 20; ++i) {
        float s = e[i] * rt;
        if (s > 0.02f) {
          u32 bits = __float_as_uint(s);
          int bk = score_bucket(bits);
          u64 key = ((u64)bits << 32) | (u64)(0xFFFFFFFFu - (u32)(a * NCLS + c0 + i));
          if (ctx < 0 || bk > ctx) {
            int p = atomicAdd(&nm, 1);
            if (p < 1024) { mk[p] = key; msg_[p] = (unsigned char)si; atomicAdd(&cm[si], 1); }
            else { u32 pg = atomicAdd(&mcount[seg], 1u); if (pg < 1024) mainG[(size_t)seg * 1024 + pg] = key; }
          } else if (bk == ctx) {
            int p = atomicAdd(&nb, 1);
            if (p < 256) { bkl[p] = key; bsg[p] = (unsigned char)si; atomicAdd(&cb[si], 1); }
            else { u32 pg = atomicAdd(&bcount[seg], 1u); if (pg < 4096) bndG[(size_t)seg * 4096 + pg] = key; }
          }
        }
      }
    }
  }
  __syncthreads();
  if (tid < nseg) {
    if (cm[tid] > 0) basem[tid] = (int)atomicAdd(&mcount[seg_lo + tid], (u32)cm[tid]);
    if (cb[tid] > 0) baseb[tid] = (int)atomicAdd(&bcount[seg_lo + tid], (u32)cb[tid]);
  }
  __syncthreads();
  int tm = nm < 1024 ? nm : 1024;
  for (int idx = tid; idx < tm; idx += FT) {
    int si = msg_[idx];
    int slot = atomicAdd(&wm[si], 1);
    int d = basem[si] + slot;
    if (d < 1024) mainG[(size_t)(seg_lo + si) * 1024 + d] = mk[idx];
  }
  int tb = nb < 256 ? nb : 256;
  for (int idx = tid; idx < tb; idx += FT) {
    int si = bsg[idx];
    int slot = atomicAdd(&wb[si], 1);
    int d = baseb[si] + slot;
    if (d < 4096) bndG[(size_t)(seg_lo + si) * 4096 + d] = bkl[idx];
  }
}

__device__ inline void bitonic_desc(u64* s, int n) {
  for (int k = 2; k <= n; k <<= 1)
    for (int j = k >> 1; j > 0; j >>= 1) {
      __syncthreads();
      for (int i = threadIdx.x; i < n; i += blockDim.x) {
        int l = i ^ j;
        if (l > i) {
          u64 a = s[i], b = s[l];
          if (((i & k) == 0) ? (a < b) : (a > b)) { s[i] = b; s[l] = a; }
        }
      }
    }
  __syncthreads();
}

// exact per-level top-k: sort only pow2ceil(boundary count) elements
__global__ __launch_bounds__(1024) void k_refine(const u32* __restrict__ histG,
                                                 const u64* __restrict__ bndG,
                                                 const u32* __restrict__ bcount,
                                                 u64* __restrict__ mainG, u32* __restrict__ mcount) {
  int seg = blockIdx.x;
  __shared__ int sh_cx, sh_cy;
  __shared__ u64 s[4096];
  int tid = threadIdx.x, lane = tid & 63;
  if (tid < 64) {
    int cx, cy;
    wave_find_cut(histG + (size_t)seg * HBUCKETS, c_klv[seg % NLV], lane, cx, cy);
    if (lane == 0) { sh_cx = cx; sh_cy = cy; }
  }
  __syncthreads();
  if (sh_cx < 0) return;
  int m = (int)bcount[seg]; if (m > 4096) m = 4096;
  int n = 64; while (n < m) n <<= 1;
  for (int t = tid; t < n; t += 1024)
    s[t] = (t < m) ? bndG[(size_t)seg * 4096 + t] : 0ULL;
  bitonic_desc(s, n);
  int kp = sh_cy; if (kp > m) kp = m;
  int base = (int)mcount[seg];
  for (int t = tid; t < kp; t += 1024) {
    int p = base + t;
    if (p < 1024) mainG[(size_t)seg * 1024 + p] = s[t];
  }
  __syncthreads();
  if (tid == 0) {
    int nb = base + kp;
    mcount[seg] = (u32)(nb > 1024 ? 1024 : nb);
  }
}

// per-image: global cut from truncated per-level histograms, then histogram
// RANK-SORT: count per bucket -> suffix-scan bases -> scatter into bucket
// segments -> exact in-bucket rank -> permute in place. Decode inline.
__global__ __launch_bounds__(1024) void k_gsel(const u32* __restrict__ histG,
                                               const u64* __restrict__ mainG,
                                               const u32* __restrict__ mcount,
                                               const float4* __restrict__ priors,
                                               const float4* __restrict__ reg,
                                               float4* __restrict__ boxesG,
                                               int* __restrict__ clsG,
                                               float* __restrict__ scoreG) {
  int img = blockIdx.x;
  int tid = threadIdx.x, wid = tid >> 6, lane = tid & 63;
  __shared__ u32 H[HBUCKETS];     // merged hist; then scan pong; then subhist
  __shared__ u32 cntb[HBUCKETS];
  __shared__ u32 Sarr[HBUCKETS];  // inclusive suffix sums
  __shared__ u32 cnt2[HBUCKETS];
  __shared__ u64 sel[CAPSEL];     // 36864 B
  __shared__ int lcx[NLV], lcy[NLV];
  __shared__ int sh_gx, sh_gy, sh_cC, sh_cand, sh_sgx;
  if (tid == 0) { sh_cC = 0; sh_cand = 0; sh_sgx = -1; }
  if (wid < NLV) {
    int cx, cy;
    wave_find_cut(histG + (size_t)(img * NLV + wid) * HBUCKETS, c_klv[wid], lane, cx, cy);
    if (lane == 0) { lcx[wid] = cx; lcy[wid] = cy; }
  }
  __syncthreads();
  for (int b = tid; b < HBUCKETS; b += 1024) {
    u32 acc = 0;
#pragma unroll
    for (int l = 0; l < NLV; ++l) {
      u32 h = histG[(size_t)(img * NLV + l) * HBUCKETS + b];
      int cx = lcx[l];
      if (cx < 0 || b > cx) acc += h;
      else if (b == cx) acc += (u32)lcy[l];
    }
    H[b] = acc;
    cntb[b] = 0;
    cnt2[b] = 0;
  }
  __syncthreads();
  if (wid == 0) {
    int gx, gy;
    wave_find_cut(H, NPRE, lane, gx, gy);
    if (lane == 0) { sh_gx = gx; sh_gy = gy; }
  }
  __syncthreads();
  int gx = sh_gx, gy = sh_gy;
  int mcap[NLV];
#pragma unroll
  for (int l = 0; l < NLV; ++l) { int c = (int)mcount[img * NLV + l]; mcap[l] = c > 1024 ? 1024 : c; }
  // count pass
  for (int l = 0; l < NLV; ++l)
    for (int t = tid; t < mcap[l]; t += 1024) {
      u64 key = mainG[(size_t)(img * NLV + l) * 1024 + t];
      int b = score_bucket((u32)(key >> 32));
      if (gx < 0 || b > gx) atomicAdd(&cntb[b], 1u);
      else if (b == gx) atomicAdd(&sh_cC, 1);
    }
  __syncthreads();
  // inclusive suffix scan cntb -> Sarr (ping-pong with H; 10 steps)
  for (int b = tid; b < HBUCKETS; b += 1024) Sarr[b] = cntb[b];
  __syncthreads();
  {
    u32* A = Sarr; u32* B = H;
    for (int o = 1; o < HBUCKETS; o <<= 1) {
      for (int b = tid; b < HBUCKETS; b += 1024)
        B[b] = A[b] + ((b + o < HBUCKETS) ? A[b + o] : 0u);
      __syncthreads();
      u32* tmp = A; A = B; B = tmp;
    }
  }
  int cA = (int)Sarr[0];
  int cC = sh_cC;
  int cand = (gx >= 0) ? cC : 0;
  int sgx = -1;
  if (gx >= 0 && cA + cC > CAPSEL) {
    // sub-refine cut bucket by next 10 mantissa bits (measure-zero branch)
    for (int b = tid; b < HBUCKETS; b += 1024) H[b] = 0;
    __syncthreads();
    for (int l = 0; l < NLV; ++l)
      for (int t = tid; t < mcap[l]; t += 1024) {
        u64 key = mainG[(size_t)(img * NLV + l) * 1024 + t];
        u32 bits = (u32)(key >> 32);
        if (score_bucket(bits) == gx) atomicAdd(&H[(bits >> 6) & 1023], 1u);
      }
    __syncthreads();
    if (wid == 0) {
      int a1, a2;
      wave_find_cut(H, gy, lane, a1, a2);
      if (lane == 0) sh_sgx = a1;
    }
    __syncthreads();
    sgx = sh_sgx;
    if (sgx >= 0) {
      for (int s2 = tid; s2 < HBUCKETS; s2 += 1024)
        if (s2 >= sgx) { u32 v = H[s2]; if (v) atomicAdd(&sh_cand, (int)v); }
      __syncthreads();
      cand = sh_cand;
    }
    if (cA + cand > CAPSEL) cand = CAPSEL - cA;  // memory-safety clamp
  }
  __syncthreads();
  // scatter pass
  for (int l = 0; l < NLV; ++l)
    for (int t = tid; t < mcap[l]; t += 1024) {
      u64 key = mainG[(size_t)(img * NLV + l) * 1024 + t];
      u32 bits = (u32)(key >> 32);
      int b = score_bucket(bits);
      bool inc = false; int segbase = 0, seglen = 0;
      if (gx < 0 || b > gx) {
        inc = true; segbase = (int)(Sarr[b] - cntb[b]); seglen = (int)cntb[b];
      } else if (b == gx) {
        inc = (sgx < 0) || ((int)((bits >> 6) & 1023) >= sgx);
        segbase = (int)Sarr[b]; seglen = cand;
      }
      if (inc) {
        int slot = (int)atomicAdd(&cnt2[b], 1u);
        if (slot < seglen) sel[segbase + slot] = key;
      }
    }
  __syncthreads();
  int total = cA + cand;
  // exact in-bucket rank sort (in-place permutation; reads before writes)
  u64 myk[5]; int myp[5];
#pragma unroll
  for (int it = 0; it < 5; ++it) {
    int t = tid + it * 1024;
    myp[it] = -1; myk[it] = 0;
    if (t < total) {
      u64 key = sel[t];
      u32 bits = (u32)(key >> 32);
      int b = score_bucket(bits);
      int segbase, seglen;
      if (gx >= 0 && b == gx) { segbase = (int)Sarr[b]; seglen = cand; }
      else { segbase = (int)(Sarr[b] - cntb[b]); seglen = (int)cntb[b]; }
      int r = 0;
      for (int u = 0; u < seglen; ++u) r += (sel[segbase + u] > key) ? 1 : 0;
      myk[it] = key; myp[it] = segbase + r;
    }
  }
  __syncthreads();
#pragma unroll
  for (int it = 0; it < 5; ++it) if (myp[it] >= 0) sel[myp[it]] = myk[it];
  __syncthreads();
  // decode
  for (int t = tid; t < NPRE; t += 1024) {
    u64 key = (t < total) ? sel[t] : 0ULL;
    float4 bx = make_float4(0.f, 0.f, 0.f, 0.f);
    int c = -1;
    float sc = 0.f;
    if (key != 0ULL) {
      sc = __uint_as_float((u32)(key >> 32));
      u32 flat = 0xFFFFFFFFu - (u32)(key & 0xFFFFFFFFULL);
      int a = (int)(flat / NCLS);
      c = (int)(flat % NCLS);
      float4 p = priors[a];
      float4 r = reg[(size_t)img * A_TOTAL + a];
      float cx = p.x + (r.x * 0.1f) * p.z;
      float cy = p.y + (r.y * 0.1f) * p.w;
      float w = p.z * expf(r.z * 0.2f);
      float h = p.w * expf(r.w * 0.2f);
      bx.x = fminf(fmaxf(cx - w * 0.5f, 0.f), 512.f);
      bx.y = fminf(fmaxf(cy - h * 0.5f, 0.f), 512.f);
      bx.z = fminf(fmaxf(cx + w * 0.5f, 0.f), 512.f);
      bx.w = fminf(fmaxf(cy + h * 0.5f, 0.f), 512.f);
    }
    boxesG[(size_t)img * NPRE + t] = bx;
    clsG[(size_t)img * NPRE + t] = c;
    scoreG[(size_t)img * NPRE + t] = sc;
  }
}

// Fused NMS: per 16-row tile, waves 1..15 compute the tile's suppression
// bitmask into LDS (double-buffered) while wave 0 serially scans the
// previous tile. Early exit at >=200 kept (~14 tiles) -> ~9x less IoU work
// than the full 2000x2000 mask, zero mask HBM traffic. Fallback (<200 kept
// after full scan): bit-identical suppressed-index padding path.
__global__ __launch_bounds__(NMST) void k_nms(const float4* __restrict__ boxesG,
                                              const int* __restrict__ clsG,
                                              const float* __restrict__ scoreG,
                                              float* __restrict__ out) {
  int img = blockIdx.x;
  int tid = threadIdx.x, wid = tid >> 6, lane = tid & 63;
  __shared__ float4 lb[NPRE];          // 32768 B
  __shared__ short lc2[NPRE];          // 4000 B
  __shared__ u64 mbuf[2][16][32];      // 8192 B
  __shared__ u64 sh_remv[32];
  __shared__ u32 keptList[216];
  __shared__ int sh_cnt, sh_done, sh_stop;
  __shared__ int kpref[NMST + 1];
  __shared__ unsigned short S[NPRE];
  if (tid == 0) { sh_cnt = 0; sh_done = 0; sh_stop = 0; }
  for (int t = tid; t < NPRE; t += NMST) {
    lb[t] = boxesG[(size_t)img * NPRE + t];
    lc2[t] = (short)clsG[(size_t)img * NPRE + t];
  }
  __syncthreads();

  // compute one row's 32 mask words into mbuf[buf][r]
  auto row_mask = [&](int t, int buf, int r) {
    int i = t * 16 + r;
    float4 bi = lb[i];
    short ci = lc2[i];
    float ai = (bi.z - bi.x) * (bi.w - bi.y);
    for (int c = 0; c < 32; ++c) {
      int j = c * 64 + lane;
      bool pred = false;
      if (j > i && lc2[j] == ci) {
        float4 bj = lb[j];
        float xx1 = fmaxf(bi.x, bj.x), yy1 = fmaxf(bi.y, bj.y);
        float xx2 = fminf(bi.z, bj.z), yy2 = fminf(bi.w, bj.w);
        float ww = fmaxf(xx2 - xx1, 0.f), hh = fmaxf(yy2 - yy1, 0.f);
        float inter = ww * hh;
        float aj = (bj.z - bj.x) * (bj.w - bj.y);
        float iou = inter / fmaxf(ai + aj - inter, 1e-6f);
        pred = iou > 0.45f;
      }
      u64 word = __ballot(pred);
      if (lane == 0) mbuf[buf][r][c] = word;
    }
  };

  // prologue: all 16 waves compute tile 0 (one row each)
  row_mask(0, 0, wid);
  __syncthreads();

  u64 remv = 0;   // wave 0 persistent state (lane wl owns word wl; mirrored)
  int cnt = 0;
  int t = 0;
  while (true) {
    if (wid > 0 && t + 1 < 125) {
      for (int r = wid - 1; r < 16; r += 15) row_mask(t + 1, (t + 1) & 1, r);
    }
    if (wid == 0) {
      int wl = lane & 31;
      for (int r = 0; r < 16; ++r) {
        int i = t * 16 + r;
        u64 cur = mbuf[t & 1][r][wl];
        u64 rm = shfl_u64(remv, i >> 6);
        if (!((rm >> (i & 63)) & 1ULL)) {
          remv |= cur;
          if (lane == 0 && cnt < 216) keptList[cnt] = (u32)i;
          ++cnt;
        }
      }
      if (lane == 0 && (cnt >= 200 || t == 124)) {
        sh_stop = 1;
        sh_cnt = cnt < 216 ? cnt : 216;
        if (cnt < 200 && t == 124) sh_done = 1;
      }
      if (t == 124 && lane < 32) sh_remv[lane] = remv;
    }
    __syncthreads();
    if (sh_stop) break;
    ++t;
  }

  int nK = sh_cnt;
  if (sh_done && nK < 200) {
    // padding path: suppressed indices ascending fill tail (jax top_k stability)
    int base = tid * 2;
    bool sb0 = false, sb1 = false;
    int scnt = 0;
    if (base < NPRE)     { sb0 = (sh_remv[base >> 6] >> (base & 63)) & 1ULL; scnt += sb0 ? 1 : 0; }
    if (base + 1 < NPRE) { sb1 = (sh_remv[(base + 1) >> 6] >> ((base + 1) & 63)) & 1ULL; scnt += sb1 ? 1 : 0; }
    kpref[tid + 1] = scnt;
    if (tid == 0) kpref[0] = 0;
    __syncthreads();
    if (tid == 0) {
      int acc = 0;
      for (int i = 1; i <= NMST; ++i) { acc += kpref[i]; kpref[i] = acc; }
    }
    __syncthreads();
    int sp = kpref[tid];
    if (base < NPRE && sb0) S[sp++] = (unsigned short)base;
    if (base + 1 < NPRE && sb1) S[sp++] = (unsigned short)(base + 1);
    __syncthreads();
    if (tid < 200) {
      float fv = 0.f;
      float4 fb = make_float4(0.f, 0.f, 0.f, 0.f);
      int fc;
      if (tid < nK) {
        int idx = (int)keptList[tid];
        fv = scoreG[(size_t)img * NPRE + idx];
        fb = lb[idx];
        fc = (int)lc2[idx];
      } else {
        int idx = S[tid - nK];
        fc = (int)lc2[idx];
      }
      float* fbo = out + (size_t)img * 800 + tid * 4;
      fbo[0] = fb.x; fbo[1] = fb.y; fbo[2] = fb.z; fbo[3] = fb.w;
      out[3200 + (size_t)img * 200 + tid] = fv;
      out[4000 + (size_t)img * 200 + tid] = (float)fc;
    }
  } else {
    if (tid < 200) {
      int idx = (int)keptList[tid];
      float fv = scoreG[(size_t)img * NPRE + idx];
      float4 fb = lb[idx];
      int fc = (int)lc2[idx];
      float* fbo = out + (size_t)img * 800 + tid * 4;
      fbo[0] = fb.x; fbo[1] = fb.y; fbo[2] = fb.z; fbo[3] = fb.w;
      out[3200 + (size_t)img * 200 + tid] = fv;
      out[4000 + (size_t)img * 200 + tid] = (float)fc;
    }
  }
}

extern "C" void kernel_launch(void* const* d_in, const int* in_sizes, int n_in,
                              void* d_out, int out_size, void* d_ws, size_t ws_size,
                              hipStream_t stream) {
  const float* logits = (const float*)d_in[0];
  const float4* reg = (const float4*)d_in[1];
  const float4* priors = (const float4*)d_in[2];
  char* ws = (char*)d_ws;
  u32* hist = (u32*)(ws + WS_HIST);
  u32* mcount = (u32*)(ws + WS_MCOUNT);
  u32* bcount = (u32*)(ws + WS_BCOUNT);
  u32* pcount = (u32*)(ws + WS_PCOUNT);
  u64* mainL = (u64*)(ws + WS_MAIN);
  u64* bndL = (u64*)(ws + WS_BND);
  float4* boxes = (float4*)(ws + WS_BOXES);
  int* cls = (int*)(ws + WS_CLS);
  float* score = (float*)(ws + WS_SCORE);
  u64* pool = (u64*)(ws + WS_POOL);

  size_t avail = ws_size > (size_t)WS_POOL ? ws_size - (size_t)WS_POOL : 0;
  int cap = (int)(avail / ((size_t)NBLK_F * 8));
  if (cap > POOL_CAP_MAX) cap = POOL_CAP_MAX;

  k_zero<<<(NZERO_W + 255) / 256, 256, 0, stream>>>((u32*)d_ws);
  k_fused<<<NBLK_F, FT, 0, stream>>>(logits, hist, pool, pcount, cap);
  k_filter<<<NBLK_F, FT, 0, stream>>>(logits, pool, pcount, hist, cap,
                                      mainL, mcount, bndL, bcount);
  k_refine<<<28, 1024, 0, stream>>>(hist, bndL, bcount, mainL, mcount);
  k_gsel<<<NIMG, 1024, 0, stream>>>(hist, mainL, mcount, priors, reg, boxes, cls, score);
  k_nms<<<NIMG, NMST, 0, stream>>>(boxes, cls, score, (float*)d_out);
}

// Round 11
// 107.205 us; speedup vs baseline: 1.9743x; 1.9743x over previous
//
#include <hip/hip_runtime.h>
#include <hip/hip_bf16.h>
#include <math.h>

typedef unsigned long long u64;
typedef unsigned int u32;

#define A_TOTAL 24564
#define NCLS 80
#define NIMG 4
#define NPRE 2000
#define NLV 7
#define HBUCKETS 1024
#define BEXP_BASE 0x3CA3
#define TOTAL_G (NIMG * A_TOTAL)   // 98256
#define FA 64                      // anchors per block (fused/filter)
#define FT 256                     // threads per block (4 per anchor)
#define NBLK_F ((TOTAL_G + FA - 1) / FA)  // 1536
#define POOL_CAP_MAX 4096
#define CAPSEL 4608
#define MROWS 512                  // mask rows computed (scan needs ~216)
#define FTILES (MROWS / 16)        // 32

__device__ __constant__ int c_klv[NLV] = {1000,1000,1000,1000,1000,1000,320};

// ---- workspace layout (bytes) ----
#define WS_HIST      0          // 28*1024*4 = 114688
#define WS_MCOUNT    114688     // 28*4
#define WS_BCOUNT    114800     // 28*4
#define WS_ZERO_END  114912     // hist+mcount+bcount only (pcount overwritten)
#define WS_PCOUNT    114912     // 1536*4 = 6144
#define WS_MAIN      121280     // 28*1024*8
#define WS_BND       350656     // 28*4096*8
#define WS_BOXES     1268160    // 4*2000*16
#define WS_CLS       1396160    // 4*2000*4
#define WS_SCORE     1428160    // 4*2000*4
#define WS_MASK      1460160    // 4*512*32*8 = 524288
#define WS_POOL      3508160    // NBLK_F * cap * 8, cap adaptive to ws_size

#define NZERO_W (WS_ZERO_END / 4)   // 28728 u32 words

__device__ inline u64 shfl_u64(u64 v, int src) {
  int lo = __shfl((int)(u32)(v & 0xFFFFFFFFULL), src);
  int hi = __shfl((int)(u32)(v >> 32), src);
  return ((u64)(u32)hi << 32) | (u32)lo;
}

__device__ inline int score_bucket(u32 bits) {
  int b = (int)(bits >> 16) - BEXP_BASE;
  return b < 0 ? 0 : (b > HBUCKETS - 1 ? HBUCKETS - 1 : b);
}

__device__ inline int level_of(int a) {
  return (a < 16384) ? 0 : (a < 22528) ? 1 : (a < 24064) ? 2 :
         (a < 24448) ? 3 : (a < 24544) ? 4 : (a < 24560) ? 5 : 6;
}

// replaces rocclr fillBufferAligned for our small zero region
__global__ __launch_bounds__(256) void k_zero(u32* __restrict__ p) {
  int i = blockIdx.x * 256 + threadIdx.x;
  if (i < NZERO_W) p[i] = 0;
}

// Registers-only softmax for one anchor, 4 threads/anchor (quad q=0..3 owns
// classes [20q,20q+20); q==3 also folds class 80 into max/sum). SINGLE
// source of truth so k_filter's fallback reproduces identical bits.
__device__ inline void score20(const float* __restrict__ logits, int g, int q,
                               float (&e)[20], float& rt) {
  const float* row = logits + (size_t)g * 81;
  float x[20];
#pragma unroll
  for (int i = 0; i < 20; ++i) x[i] = row[q * 20 + i];
  float x80 = (q == 3) ? row[80] : 0.f;
  float mloc = x[0];
#pragma unroll
  for (int i = 1; i < 20; ++i) mloc = fmaxf(mloc, x[i]);
  if (q == 3) mloc = fmaxf(mloc, x80);
  float m = fmaxf(mloc, __shfl_xor(mloc, 1));
  m = fmaxf(m, __shfl_xor(m, 2));
  float tq = 0.f;
#pragma unroll
  for (int i = 0; i < 20; ++i) { e[i] = expf(x[i] - m); tq += e[i]; }
  if (q == 3) tq += expf(x80 - m);
  float t = tq + __shfl_xor(tq, 1);
  t = t + __shfl_xor(t, 2);
  rt = 1.0f / t;
}

// One full wave finds (cut bucket, count-in-bucket) for top-k over a 1024-bin
// histogram h. Deterministic: same h,k -> same result.
__device__ inline void wave_find_cut(const u32* __restrict__ h, int k, int lane,
                                     int& cx, int& cy) {
  u32 s = 0;
#pragma unroll
  for (int i = 0; i < 16; ++i) s += h[lane * 16 + i];
  u32 S = s;  // inclusive suffix-sum across lanes
#pragma unroll
  for (int o = 1; o < 64; o <<= 1) {
    u32 t = (u32)__shfl_down((int)S, o);
    if (lane + o < 64) S += t;
  }
  u32 total = (u32)__shfl((int)S, 0);
  if (total <= (u32)k) { cx = -1; cy = 0; return; }
  u64 bm = __ballot(S >= (u32)k);
  int L0 = 63 - (int)__clzll((long long)bm);
  u32 Sup = (u32)__shfl_down((int)S, 1);
  if (lane == 63) Sup = 0;
  int rcx = 0, rcy = 0;
  if (lane == L0) {
    u32 cum = Sup;
    for (int i = 15; i >= 0; --i) {
      u32 c = h[lane * 16 + i];
      if (cum + c >= (u32)k) { rcx = lane * 16 + i; rcy = k - (int)cum; break; }
      cum += c;
    }
  }
  cx = __shfl(rcx, L0);
  cy = __shfl(rcy, L0);
}

// Single scoring pass: registers-only softmax, per-seg score histogram,
// emission of ALL above-threshold keys into this block's pool slice.
__global__ __launch_bounds__(FT) void k_fused(const float* __restrict__ logits,
                                              u32* __restrict__ histG,
                                              u64* __restrict__ pool,
                                              u32* __restrict__ pcount, int cap) {
  __shared__ u32 sh[HBUCKETS];    // 4096 B
  __shared__ int nm;
  int tid = threadIdx.x, bx = blockIdx.x;
  for (int b = tid; b < HBUCKETS; b += FT) sh[b] = 0;
  if (tid == 0) nm = 0;
  int la = tid >> 2, q = tid & 3;
  int g = bx * FA + la;
  bool valid = g < TOTAL_G;
  int g0 = bx * FA;
  int seg0 = (g0 / A_TOTAL) * NLV + level_of(g0 % A_TOTAL);
  int seg = seg0, a = 0;
  float e[20];
  float rt = 0.f;
  if (valid) {
    int img = g / A_TOTAL;
    a = g - img * A_TOTAL;
    seg = img * NLV + level_of(a);
    score20(logits, g, q, e, rt);
  }
  int uniform = __syncthreads_and((int)(!valid || seg == seg0));
  if (valid) {
    u32* hdst = uniform ? sh : (histG + (size_t)seg * HBUCKETS);
    int c0 = q * 20;
    u32 wmask = 0;
#pragma unroll
    for (int i = 0; i < 20; ++i) {
      float s = e[i] * rt;
      if (s > 0.02f) wmask |= (1u << i);
    }
    int cnt = __popc(wmask);
    int basep = 0;
    if (cnt) basep = atomicAdd(&nm, cnt);
    while (wmask) {
      int i = __ffs(wmask) - 1;
      wmask &= wmask - 1;
      float s = e[i] * rt;
      u32 bits = __float_as_uint(s);
      atomicAdd(&hdst[score_bucket(bits)], 1u);
      if (basep < cap)
        pool[(size_t)bx * cap + basep] =
            ((u64)bits << 32) | (u64)(0xFFFFFFFFu - (u32)(a * NCLS + c0 + i));
      ++basep;
    }
  }
  __syncthreads();
  if (uniform) {
    u32* hseg = histG + (size_t)seg0 * HBUCKETS;
    for (int b = tid; b < HBUCKETS; b += FT) {
      u32 v = sh[b];
      if (v) atomicAdd(&hseg[b], v);
    }
  }
  if (tid == 0) pcount[bx] = (u32)nm;
}

// Stream this block's pool slice; per-block cut re-derivation (<=4 segs,
// deterministic from histG). Fallback (pool overflow, statistically never):
// registers-only recompute via score20 -> identical bits.
__global__ __launch_bounds__(FT) void k_filter(const float* __restrict__ logits,
                                               const u64* __restrict__ pool,
                                               const u32* __restrict__ pcount,
                                               const u32* __restrict__ histG, int cap,
                                               u64* __restrict__ mainG, u32* __restrict__ mcount,
                                               u64* __restrict__ bndG, u32* __restrict__ bcount) {
  __shared__ int lcx4[4];
  __shared__ u64 mk[1024]; __shared__ unsigned char msg_[1024];
  __shared__ u64 bkl[256]; __shared__ unsigned char bsg[256];
  __shared__ int nm, nb, cm[4], cb[4], basem[4], baseb[4], wm[4], wb[4];
  int tid = threadIdx.x, bx = blockIdx.x;
  if (tid < 4) { cm[tid] = 0; cb[tid] = 0; wm[tid] = 0; wb[tid] = 0; }
  if (tid == 0) { nm = 0; nb = 0; }
  int g0 = bx * FA;
  int img0 = g0 / A_TOTAL;
  int alo = g0 - img0 * A_TOTAL;
  int gN = g0 + FA - 1; if (gN > TOTAL_G - 1) gN = TOTAL_G - 1;
  int seg_lo = img0 * NLV + level_of(alo);
  int seg_hi = (gN / A_TOTAL) * NLV + level_of(gN % A_TOTAL);
  int nseg = seg_hi - seg_lo + 1;   // <= 4 by construction
  int wid = tid >> 6, lane = tid & 63;
  if (wid < nseg) {
    int cx, cy;
    wave_find_cut(histG + (size_t)(seg_lo + wid) * HBUCKETS,
                  c_klv[(seg_lo + wid) % NLV], lane, cx, cy);
    if (lane == 0) lcx4[wid] = cx;
  }
  __syncthreads();
  int n = (int)pcount[bx];
  if (n <= cap) {
    for (int t = tid; t < n; t += FT) {
      u64 key = pool[(size_t)bx * cap + t];
      u32 bits = (u32)(key >> 32);
      u32 flat = 0xFFFFFFFFu - (u32)(key & 0xFFFFFFFFULL);
      int a = (int)(flat / NCLS);
      int img = (a >= alo) ? img0 : img0 + 1;
      int seg = img * NLV + level_of(a);
      int si = seg - seg_lo;
      int ctx = lcx4[si];
      int bk = score_bucket(bits);
      if (ctx < 0 || bk > ctx) {
        int p = atomicAdd(&nm, 1);
        if (p < 1024) { mk[p] = key; msg_[p] = (unsigned char)si; atomicAdd(&cm[si], 1); }
        else { u32 pg = atomicAdd(&mcount[seg], 1u); if (pg < 1024) mainG[(size_t)seg * 1024 + pg] = key; }
      } else if (bk == ctx) {
        int p = atomicAdd(&nb, 1);
        if (p < 256) { bkl[p] = key; bsg[p] = (unsigned char)si; atomicAdd(&cb[si], 1); }
        else { u32 pg = atomicAdd(&bcount[seg], 1u); if (pg < 4096) bndG[(size_t)seg * 4096 + pg] = key; }
      }
    }
  } else {
    int la = tid >> 2, q = tid & 3;
    int g = g0 + la;
    if (g < TOTAL_G) {
      int img = g / A_TOTAL;
      int a = g - img * A_TOTAL;
      int seg = img * NLV + level_of(a);
      int si = seg - seg_lo;
      int ctx = lcx4[si];
      float e[20];
      float rt;
      score20(logits, g, q, e, rt);
      int c0 = q * 20;
      for (int i = 0; i < 20; ++i) {
        float s = e[i] * rt;
        if (s > 0.02f) {
          u32 bits = __float_as_uint(s);
          int bk = score_bucket(bits);
          u64 key = ((u64)bits << 32) | (u64)(0xFFFFFFFFu - (u32)(a * NCLS + c0 + i));
          if (ctx < 0 || bk > ctx) {
            int p = atomicAdd(&nm, 1);
            if (p < 1024) { mk[p] = key; msg_[p] = (unsigned char)si; atomicAdd(&cm[si], 1); }
            else { u32 pg = atomicAdd(&mcount[seg], 1u); if (pg < 1024) mainG[(size_t)seg * 1024 + pg] = key; }
          } else if (bk == ctx) {
            int p = atomicAdd(&nb, 1);
            if (p < 256) { bkl[p] = key; bsg[p] = (unsigned char)si; atomicAdd(&cb[si], 1); }
            else { u32 pg = atomicAdd(&bcount[seg], 1u); if (pg < 4096) bndG[(size_t)seg * 4096 + pg] = key; }
          }
        }
      }
    }
  }
  __syncthreads();
  if (tid < nseg) {
    if (cm[tid] > 0) basem[tid] = (int)atomicAdd(&mcount[seg_lo + tid], (u32)cm[tid]);
    if (cb[tid] > 0) baseb[tid] = (int)atomicAdd(&bcount[seg_lo + tid], (u32)cb[tid]);
  }
  __syncthreads();
  int tm = nm < 1024 ? nm : 1024;
  for (int idx = tid; idx < tm; idx += FT) {
    int si = msg_[idx];
    int slot = atomicAdd(&wm[si], 1);
    int d = basem[si] + slot;
    if (d < 1024) mainG[(size_t)(seg_lo + si) * 1024 + d] = mk[idx];
  }
  int tb = nb < 256 ? nb : 256;
  for (int idx = tid; idx < tb; idx += FT) {
    int si = bsg[idx];
    int slot = atomicAdd(&wb[si], 1);
    int d = baseb[si] + slot;
    if (d < 4096) bndG[(size_t)(seg_lo + si) * 4096 + d] = bkl[idx];
  }
}

__device__ inline void bitonic_desc(u64* s, int n) {
  for (int k = 2; k <= n; k <<= 1)
    for (int j = k >> 1; j > 0; j >>= 1) {
      __syncthreads();
      for (int i = threadIdx.x; i < n; i += blockDim.x) {
        int l = i ^ j;
        if (l > i) {
          u64 a = s[i], b = s[l];
          if (((i & k) == 0) ? (a < b) : (a > b)) { s[i] = b; s[l] = a; }
        }
      }
    }
  __syncthreads();
}

// exact per-level top-k: sort only pow2ceil(boundary count) elements
__global__ __launch_bounds__(1024) void k_refine(const u32* __restrict__ histG,
                                                 const u64* __restrict__ bndG,
                                                 const u32* __restrict__ bcount,
                                                 u64* __restrict__ mainG, u32* __restrict__ mcount) {
  int seg = blockIdx.x;
  __shared__ int sh_cx, sh_cy;
  __shared__ u64 s[4096];
  int tid = threadIdx.x, lane = tid & 63;
  if (tid < 64) {
    int cx, cy;
    wave_find_cut(histG + (size_t)seg * HBUCKETS, c_klv[seg % NLV], lane, cx, cy);
    if (lane == 0) { sh_cx = cx; sh_cy = cy; }
  }
  __syncthreads();
  if (sh_cx < 0) return;
  int m = (int)bcount[seg]; if (m > 4096) m = 4096;
  int n = 64; while (n < m) n <<= 1;
  for (int t = tid; t < n; t += 1024)
    s[t] = (t < m) ? bndG[(size_t)seg * 4096 + t] : 0ULL;
  bitonic_desc(s, n);
  int kp = sh_cy; if (kp > m) kp = m;
  int base = (int)mcount[seg];
  for (int t = tid; t < kp; t += 1024) {
    int p = base + t;
    if (p < 1024) mainG[(size_t)seg * 1024 + p] = s[t];
  }
  __syncthreads();
  if (tid == 0) {
    int nb = base + kp;
    mcount[seg] = (u32)(nb > 1024 ? 1024 : nb);
  }
}

// per-image: global cut from truncated per-level histograms, then histogram
// RANK-SORT: count per bucket -> suffix-scan bases -> scatter into bucket
// segments -> exact in-bucket rank -> permute in place. Decode inline.
__global__ __launch_bounds__(1024) void k_gsel(const u32* __restrict__ histG,
                                               const u64* __restrict__ mainG,
                                               const u32* __restrict__ mcount,
                                               const float4* __restrict__ priors,
                                               const float4* __restrict__ reg,
                                               float4* __restrict__ boxesG,
                                               int* __restrict__ clsG,
                                               float* __restrict__ scoreG) {
  int img = blockIdx.x;
  int tid = threadIdx.x, wid = tid >> 6, lane = tid & 63;
  __shared__ u32 H[HBUCKETS];     // merged hist; then scan pong; then subhist
  __shared__ u32 cntb[HBUCKETS];
  __shared__ u32 Sarr[HBUCKETS];  // inclusive suffix sums
  __shared__ u32 cnt2[HBUCKETS];
  __shared__ u64 sel[CAPSEL];     // 36864 B
  __shared__ int lcx[NLV], lcy[NLV];
  __shared__ int sh_gx, sh_gy, sh_cC, sh_cand, sh_sgx;
  if (tid == 0) { sh_cC = 0; sh_cand = 0; sh_sgx = -1; }
  if (wid < NLV) {
    int cx, cy;
    wave_find_cut(histG + (size_t)(img * NLV + wid) * HBUCKETS, c_klv[wid], lane, cx, cy);
    if (lane == 0) { lcx[wid] = cx; lcy[wid] = cy; }
  }
  __syncthreads();
  for (int b = tid; b < HBUCKETS; b += 1024) {
    u32 acc = 0;
#pragma unroll
    for (int l = 0; l < NLV; ++l) {
      u32 h = histG[(size_t)(img * NLV + l) * HBUCKETS + b];
      int cx = lcx[l];
      if (cx < 0 || b > cx) acc += h;
      else if (b == cx) acc += (u32)lcy[l];
    }
    H[b] = acc;
    cntb[b] = 0;
    cnt2[b] = 0;
  }
  __syncthreads();
  if (wid == 0) {
    int gx, gy;
    wave_find_cut(H, NPRE, lane, gx, gy);
    if (lane == 0) { sh_gx = gx; sh_gy = gy; }
  }
  __syncthreads();
  int gx = sh_gx, gy = sh_gy;
  int mcap[NLV];
#pragma unroll
  for (int l = 0; l < NLV; ++l) { int c = (int)mcount[img * NLV + l]; mcap[l] = c > 1024 ? 1024 : c; }
  // count pass
  for (int l = 0; l < NLV; ++l)
    for (int t = tid; t < mcap[l]; t += 1024) {
      u64 key = mainG[(size_t)(img * NLV + l) * 1024 + t];
      int b = score_bucket((u32)(key >> 32));
      if (gx < 0 || b > gx) atomicAdd(&cntb[b], 1u);
      else if (b == gx) atomicAdd(&sh_cC, 1);
    }
  __syncthreads();
  // inclusive suffix scan cntb -> Sarr (ping-pong with H; 10 steps)
  for (int b = tid; b < HBUCKETS; b += 1024) Sarr[b] = cntb[b];
  __syncthreads();
  {
    u32* A = Sarr; u32* B = H;
    for (int o = 1; o < HBUCKETS; o <<= 1) {
      for (int b = tid; b < HBUCKETS; b += 1024)
        B[b] = A[b] + ((b + o < HBUCKETS) ? A[b + o] : 0u);
      __syncthreads();
      u32* tmp = A; A = B; B = tmp;
    }
  }
  int cA = (int)Sarr[0];
  int cC = sh_cC;
  int cand = (gx >= 0) ? cC : 0;
  int sgx = -1;
  if (gx >= 0 && cA + cC > CAPSEL) {
    // sub-refine cut bucket by next 10 mantissa bits (measure-zero branch)
    for (int b = tid; b < HBUCKETS; b += 1024) H[b] = 0;
    __syncthreads();
    for (int l = 0; l < NLV; ++l)
      for (int t = tid; t < mcap[l]; t += 1024) {
        u64 key = mainG[(size_t)(img * NLV + l) * 1024 + t];
        u32 bits = (u32)(key >> 32);
        if (score_bucket(bits) == gx) atomicAdd(&H[(bits >> 6) & 1023], 1u);
      }
    __syncthreads();
    if (wid == 0) {
      int a1, a2;
      wave_find_cut(H, gy, lane, a1, a2);
      if (lane == 0) sh_sgx = a1;
    }
    __syncthreads();
    sgx = sh_sgx;
    if (sgx >= 0) {
      for (int s2 = tid; s2 < HBUCKETS; s2 += 1024)
        if (s2 >= sgx) { u32 v = H[s2]; if (v) atomicAdd(&sh_cand, (int)v); }
      __syncthreads();
      cand = sh_cand;
    }
    if (cA + cand > CAPSEL) cand = CAPSEL - cA;  // memory-safety clamp
  }
  __syncthreads();
  // scatter pass
  for (int l = 0; l < NLV; ++l)
    for (int t = tid; t < mcap[l]; t += 1024) {
      u64 key = mainG[(size_t)(img * NLV + l) * 1024 + t];
      u32 bits = (u32)(key >> 32);
      int b = score_bucket(bits);
      bool inc = false; int segbase = 0, seglen = 0;
      if (gx < 0 || b > gx) {
        inc = true; segbase = (int)(Sarr[b] - cntb[b]); seglen = (int)cntb[b];
      } else if (b == gx) {
        inc = (sgx < 0) || ((int)((bits >> 6) & 1023) >= sgx);
        segbase = (int)Sarr[b]; seglen = cand;
      }
      if (inc) {
        int slot = (int)atomicAdd(&cnt2[b], 1u);
        if (slot < seglen) sel[segbase + slot] = key;
      }
    }
  __syncthreads();
  int total = cA + cand;
  // exact in-bucket rank sort (in-place permutation; reads before writes)
  u64 myk[5]; int myp[5];
#pragma unroll
  for (int it = 0; it < 5; ++it) {
    int t = tid + it * 1024;
    myp[it] = -1; myk[it] = 0;
    if (t < total) {
      u64 key = sel[t];
      u32 bits = (u32)(key >> 32);
      int b = score_bucket(bits);
      int segbase, seglen;
      if (gx >= 0 && b == gx) { segbase = (int)Sarr[b]; seglen = cand; }
      else { segbase = (int)(Sarr[b] - cntb[b]); seglen = (int)cntb[b]; }
      int r = 0;
      for (int u = 0; u < seglen; ++u) r += (sel[segbase + u] > key) ? 1 : 0;
      myk[it] = key; myp[it] = segbase + r;
    }
  }
  __syncthreads();
#pragma unroll
  for (int it = 0; it < 5; ++it) if (myp[it] >= 0) sel[myp[it]] = myk[it];
  __syncthreads();
  // decode
  for (int t = tid; t < NPRE; t += 1024) {
    u64 key = (t < total) ? sel[t] : 0ULL;
    float4 bx = make_float4(0.f, 0.f, 0.f, 0.f);
    int c = -1;
    float sc = 0.f;
    if (key != 0ULL) {
      sc = __uint_as_float((u32)(key >> 32));
      u32 flat = 0xFFFFFFFFu - (u32)(key & 0xFFFFFFFFULL);
      int a = (int)(flat / NCLS);
      c = (int)(flat % NCLS);
      float4 p = priors[a];
      float4 r = reg[(size_t)img * A_TOTAL + a];
      float cx = p.x + (r.x * 0.1f) * p.z;
      float cy = p.y + (r.y * 0.1f) * p.w;
      float w = p.z * expf(r.z * 0.2f);
      float h = p.w * expf(r.w * 0.2f);
      bx.x = fminf(fmaxf(cx - w * 0.5f, 0.f), 512.f);
      bx.y = fminf(fmaxf(cy - h * 0.5f, 0.f), 512.f);
      bx.z = fminf(fmaxf(cx + w * 0.5f, 0.f), 512.f);
      bx.w = fminf(fmaxf(cy + h * 0.5f, 0.f), 512.f);
    }
    boxesG[(size_t)img * NPRE + t] = bx;
    clsG[(size_t)img * NPRE + t] = c;
    scoreG[(size_t)img * NPRE + t] = sc;
  }
}

// suppression bitmask for rows < MROWS only (scan consumes ~216 rows before
// reaching 200 kept): row i, bit j set iff j>i, same class, IoU>0.45
__global__ __launch_bounds__(256) void k_mask(const float4* __restrict__ boxesG,
                                              const int* __restrict__ clsG,
                                              u64* __restrict__ maskG) {
  __shared__ float4 lb[NPRE];
  __shared__ short lc[NPRE];
  int img = blockIdx.x / (MROWS / 4);
  int rb = (blockIdx.x % (MROWS / 4)) * 4;
  for (int t = threadIdx.x; t < NPRE; t += 256) {
    lb[t] = boxesG[(size_t)img * NPRE + t];
    lc[t] = (short)clsG[(size_t)img * NPRE + t];
  }
  __syncthreads();
  int w = threadIdx.x >> 6, lane = threadIdx.x & 63;
  int i = rb + w;
  float4 bi = lb[i];
  short ci = lc[i];
  float ai = (bi.z - bi.x) * (bi.w - bi.y);
  u64* mrow = maskG + ((size_t)img * MROWS + i) * 32;
  for (int ch = 0; ch < 32; ++ch) {
    int j = ch * 64 + lane;
    bool pred = false;
    if (j < NPRE && j > i) {
      if (lc[j] == ci) {
        float4 bj = lb[j];
        float xx1 = fmaxf(bi.x, bj.x), yy1 = fmaxf(bi.y, bj.y);
        float xx2 = fminf(bi.z, bj.z), yy2 = fminf(bi.w, bj.w);
        float ww = fmaxf(xx2 - xx1, 0.f), hh = fmaxf(yy2 - yy1, 0.f);
        float inter = ww * hh;
        float aj = (bj.z - bj.x) * (bj.w - bj.y);
        float iou = inter / fmaxf(ai + aj - inter, 1e-6f);
        pred = iou > 0.45f;
      }
    }
    u64 word = __ballot(pred);
    if (lane == 0) mrow[ch] = word;
  }
}

// greedy scan over precomputed mask rows (tiles 0..FTILES-1) with early exit
// at 200 kept; statistically-never tail (<200 kept in MROWS rows): compute
// remaining tiles' masks on the fly (4 waves -> LDS -> scan). Fused gather.
__global__ __launch_bounds__(256) void k_scanfinal(const u64* __restrict__ maskG,
                                                   const float4* __restrict__ boxesG,
                                                   const int* __restrict__ clsG,
                                                   const float* __restrict__ scoreG,
                                                   float* __restrict__ out) {
  int img = blockIdx.x;
  int tid = threadIdx.x;
  int wid = tid >> 6, lane = tid & 63;
  __shared__ u64 sh_remv[32];
  __shared__ u64 fbm[16][32];
  __shared__ u32 keptList[216];
  __shared__ int sh_cnt, sh_done, sh_fall, sh_stop;
  __shared__ int kpref[257];
  __shared__ unsigned short S[NPRE];
  if (tid == 0) { sh_cnt = 0; sh_done = 0; sh_fall = 0; sh_stop = 0; }
  __syncthreads();
  u64 remv = 0;   // wave 0 persistent scan state (lane wl owns word wl)
  int cnt = 0;
  if (tid < 64) {
    int wl = lane & 31;
    const u64* M = maskG + (size_t)img * MROWS * 32;
    u64 cur[16], nxt[16];
#pragma unroll
    for (int r = 0; r < 16; ++r) cur[r] = M[(size_t)r * 32 + wl];
    for (int t = 0; t < FTILES; ++t) {
      if (t < FTILES - 1) {
#pragma unroll
        for (int r = 0; r < 16; ++r) nxt[r] = M[(size_t)((t + 1) * 16 + r) * 32 + wl];
      }
#pragma unroll
      for (int r = 0; r < 16; ++r) {
        int i = t * 16 + r;
        u64 rm = shfl_u64(remv, i >> 6);
        if (!((rm >> (i & 63)) & 1ULL)) {
          remv |= cur[r];
          if (lane == 0 && cnt < 216) keptList[cnt] = (u32)i;
          ++cnt;
        }
      }
#pragma unroll
      for (int r = 0; r < 16; ++r) cur[r] = nxt[r];
      if (cnt >= 200) break;
    }
    if (lane == 0) { sh_cnt = cnt < 216 ? cnt : 216; sh_fall = (cnt < 200) ? 1 : 0; }
  }
  __syncthreads();
  if (sh_fall) {
    // tail fallback: compute tiles FTILES..124 on the fly, then scan
    for (int ft = FTILES; ft < 125; ++ft) {
      for (int r = wid; r < 16; r += 4) {
        int i = ft * 16 + r;
        float4 bi = boxesG[(size_t)img * NPRE + i];
        int ci = clsG[(size_t)img * NPRE + i];
        float ai = (bi.z - bi.x) * (bi.w - bi.y);
        for (int ch = 0; ch < 32; ++ch) {
          int j = ch * 64 + lane;
          bool pred = false;
          if (j < NPRE && j > i && clsG[(size_t)img * NPRE + j] == ci) {
            float4 bj = boxesG[(size_t)img * NPRE + j];
            float xx1 = fmaxf(bi.x, bj.x), yy1 = fmaxf(bi.y, bj.y);
            float xx2 = fminf(bi.z, bj.z), yy2 = fminf(bi.w, bj.w);
            float ww = fmaxf(xx2 - xx1, 0.f), hh = fmaxf(yy2 - yy1, 0.f);
            float inter = ww * hh;
            float aj = (bj.z - bj.x) * (bj.w - bj.y);
            float iou = inter / fmaxf(ai + aj - inter, 1e-6f);
            pred = iou > 0.45f;
          }
          u64 word = __ballot(pred);
          if (lane == 0) fbm[r][ch] = word;
        }
      }
      __syncthreads();
      if (tid < 64) {
        int wl = lane & 31;
#pragma unroll
        for (int r = 0; r < 16; ++r) {
          int i = ft * 16 + r;
          u64 rm = shfl_u64(remv, i >> 6);
          if (!((rm >> (i & 63)) & 1ULL)) {
            remv |= fbm[r][wl];
            if (lane == 0 && cnt < 216) keptList[cnt] = (u32)i;
            ++cnt;
          }
        }
        if (lane == 0 && (cnt >= 200 || ft == 124)) {
          sh_stop = 1;
          sh_cnt = cnt < 216 ? cnt : 216;
          if (cnt < 200) sh_done = 1;
        }
        if (ft == 124 && lane < 32) sh_remv[lane] = remv;
      }
      __syncthreads();
      if (sh_stop) break;
    }
  }
  __syncthreads();
  int nK = sh_cnt;
  if (sh_done && nK < 200) {
    // padding path: suppressed indices ascending fill tail (jax top_k stability)
    int base = tid * 8;
    bool sb[8];
    int scnt = 0;
#pragma unroll
    for (int e = 0; e < 8; ++e) {
      int i = base + e;
      bool sup = (i < NPRE) && ((sh_remv[i >> 6] >> (i & 63)) & 1ULL);
      sb[e] = sup;
      scnt += sup ? 1 : 0;
    }
    kpref[tid + 1] = scnt;
    if (tid == 0) kpref[0] = 0;
    __syncthreads();
    if (tid == 0) {
      int acc = 0;
      for (int t = 1; t <= 256; ++t) { acc += kpref[t]; kpref[t] = acc; }
    }
    __syncthreads();
    int sp = kpref[tid];
#pragma unroll
    for (int e = 0; e < 8; ++e) {
      int i = base + e;
      if (i < NPRE && sb[e]) S[sp++] = (unsigned short)i;
    }
    __syncthreads();
    if (tid < 200) {
      float fv = 0.f;
      float4 fb = make_float4(0.f, 0.f, 0.f, 0.f);
      int fc;
      if (tid < nK) {
        int idx = (int)keptList[tid];
        fv = scoreG[(size_t)img * NPRE + idx];
        fb = boxesG[(size_t)img * NPRE + idx];
        fc = clsG[(size_t)img * NPRE + idx];
      } else {
        int idx = S[tid - nK];
        fc = clsG[(size_t)img * NPRE + idx];
      }
      float* fbo = out + (size_t)img * 800 + tid * 4;
      fbo[0] = fb.x; fbo[1] = fb.y; fbo[2] = fb.z; fbo[3] = fb.w;
      out[3200 + (size_t)img * 200 + tid] = fv;
      out[4000 + (size_t)img * 200 + tid] = (float)fc;
    }
  } else {
    if (tid < 200) {
      int idx = (int)keptList[tid];
      float fv = scoreG[(size_t)img * NPRE + idx];
      float4 fb = boxesG[(size_t)img * NPRE + idx];
      int fc = clsG[(size_t)img * NPRE + idx];
      float* fbo = out + (size_t)img * 800 + tid * 4;
      fbo[0] = fb.x; fbo[1] = fb.y; fbo[2] = fb.z; fbo[3] = fb.w;
      out[3200 + (size_t)img * 200 + tid] = fv;
      out[4000 + (size_t)img * 200 + tid] = (float)fc;
    }
  }
}

extern "C" void kernel_launch(void* const* d_in, const int* in_sizes, int n_in,
                              void* d_out, int out_size, void* d_ws, size_t ws_size,
                              hipStream_t stream) {
  const float* logits = (const float*)d_in[0];
  const float4* reg = (const float4*)d_in[1];
  const float4* priors = (const float4*)d_in[2];
  char* ws = (char*)d_ws;
  u32* hist = (u32*)(ws + WS_HIST);
  u32* mcount = (u32*)(ws + WS_MCOUNT);
  u32* bcount = (u32*)(ws + WS_BCOUNT);
  u32* pcount = (u32*)(ws + WS_PCOUNT);
  u64* mainL = (u64*)(ws + WS_MAIN);
  u64* bndL = (u64*)(ws + WS_BND);
  float4* boxes = (float4*)(ws + WS_BOXES);
  int* cls = (int*)(ws + WS_CLS);
  float* score = (float*)(ws + WS_SCORE);
  u64* mask = (u64*)(ws + WS_MASK);
  u64* pool = (u64*)(ws + WS_POOL);

  size_t avail = ws_size > (size_t)WS_POOL ? ws_size - (size_t)WS_POOL : 0;
  int cap = (int)(avail / ((size_t)NBLK_F * 8));
  if (cap > POOL_CAP_MAX) cap = POOL_CAP_MAX;

  k_zero<<<(NZERO_W + 255) / 256, 256, 0, stream>>>((u32*)d_ws);
  k_fused<<<NBLK_F, FT, 0, stream>>>(logits, hist, pool, pcount, cap);
  k_filter<<<NBLK_F, FT, 0, stream>>>(logits, pool, pcount, hist, cap,
                                      mainL, mcount, bndL, bcount);
  k_refine<<<28, 1024, 0, stream>>>(hist, bndL, bcount, mainL, mcount);
  k_gsel<<<NIMG, 1024, 0, stream>>>(hist, mainL, mcount, priors, reg, boxes, cls, score);
  k_mask<<<NIMG * (MROWS / 4), 256, 0, stream>>>(boxes, cls, mask);
  k_scanfinal<<<NIMG, 256, 0, stream>>>(mask, boxes, cls, score, (float*)d_out);
}